// Round 2
// baseline (389.892 us; speedup 1.0000x reference)
//
#include <hip/hip_runtime.h>
#include <hip/hip_bf16.h>

#define NN 50000
#define EE 600000
#define SREP 64   // stats replicas (atomic decontention)
#define SCB 49    // scan blocks: 49 x 1024 elems >= NN

typedef short bf16x8 __attribute__((ext_vector_type(8)));
typedef float f32x4 __attribute__((ext_vector_type(4)));

__device__ inline ushort f2bf(float x) {  // round-to-nearest-even bf16
  unsigned u = __float_as_uint(x);
  u = (u + 0x7fffu + ((u >> 16) & 1u)) >> 16;
  return (ushort)u;
}
__device__ inline float bflo(uint t) { return __uint_as_float(t << 16); }
__device__ inline float bfhi(uint t) { return __uint_as_float(t & 0xffff0000u); }
__device__ inline uint f22bf(float a, float b) { return ((uint)f2bf(b) << 16) | (uint)f2bf(a); }

// ---------- graph preprocessing (CSR by destination) ----------
__global__ void count_k(const int* __restrict__ ei, int* __restrict__ cnt_d) {
  int e = blockIdx.x * 256 + threadIdx.x;
  if (e < EE) atomicAdd(&cnt_d[ei[EE + e]], 1);
}

__global__ __launch_bounds__(256) void scanA_k(const int* __restrict__ cnt,
                                               int* __restrict__ cur,
                                               int* __restrict__ bsum) {
  __shared__ int ls[256];
  const int t = threadIdx.x;
  const int base = blockIdx.x * 1024 + t * 4;
  int4 v = {0, 0, 0, 0};
  if (base + 3 < NN) v = *(const int4*)(cnt + base);
  else {
    if (base + 0 < NN) v.x = cnt[base + 0];
    if (base + 1 < NN) v.y = cnt[base + 1];
    if (base + 2 < NN) v.z = cnt[base + 2];
  }
  ls[t] = v.x + v.y + v.z + v.w;
  __syncthreads();
  for (int off = 1; off < 256; off <<= 1) {
    int u = (t >= off) ? ls[t - off] : 0;
    __syncthreads();
    ls[t] += u;
    __syncthreads();
  }
  int ex = (t == 0) ? 0 : ls[t - 1];
  int4 o;
  o.x = ex;
  o.y = ex + v.x;
  o.z = o.y + v.y;
  o.w = o.z + v.z;
  if (base + 3 < NN) *(int4*)(cur + base) = o;
  else {
    if (base + 0 < NN) cur[base + 0] = o.x;
    if (base + 1 < NN) cur[base + 1] = o.y;
    if (base + 2 < NN) cur[base + 2] = o.z;
  }
  if (t == 255) bsum[blockIdx.x] = ls[255];
}

__global__ __launch_bounds__(64) void scanB_k(int* __restrict__ bsum) {
  int t = threadIdx.x;
  int own = (t < SCB) ? bsum[t] : 0;
  int v = own;
#pragma unroll
  for (int off = 1; off < 64; off <<= 1) {
    int u = __shfl_up(v, off, 64);
    if (t >= off) v += u;
  }
  if (t < SCB) bsum[t] = v - own;
}

// writes final exclusive scan to BOTH rowp (kept) and cur (bumped by fill_k)
__global__ __launch_bounds__(256) void scanC_k(int* __restrict__ cur,
                                               const int* __restrict__ bsum,
                                               const int* __restrict__ cnt_d,
                                               int* __restrict__ rowp,
                                               float* __restrict__ invd) {
  const int t = threadIdx.x;
  const int base = blockIdx.x * 1024 + t * 4;
  const int off = bsum[blockIdx.x];
  if (base + 3 < NN) {
    int4 v = *(int4*)(cur + base);
    v.x += off; v.y += off; v.z += off; v.w += off;
    *(int4*)(cur + base) = v;
    *(int4*)(rowp + base) = v;
    int4 cd = *(const int4*)(cnt_d + base);
    float4 iv;
    iv.x = 1.0f / (float)max(cd.x, 1);
    iv.y = 1.0f / (float)max(cd.y, 1);
    iv.z = 1.0f / (float)max(cd.z, 1);
    iv.w = 1.0f / (float)max(cd.w, 1);
    *(float4*)(invd + base) = iv;
  } else {
    for (int i = 0; i < 4; ++i) {
      if (base + i < NN) {
        int v = cur[base + i] + off;
        cur[base + i] = v;
        rowp[base + i] = v;
        invd[base + i] = 1.0f / (float)max(cnt_d[base + i], 1);
      }
    }
  }
}

__global__ void fill_k(const int* __restrict__ ei, const float* __restrict__ ew,
                       int* __restrict__ cur_d, int2* __restrict__ eL) {
  int e = blockIdx.x * 256 + threadIdx.x;
  if (e < EE) {
    int s = ei[e], d = ei[EE + e];
    int pc = atomicAdd(&cur_d[d], 1);
    int2 v;
    v.x = s;
    v.y = __float_as_int(ew[e]);
    eL[pc] = v;
  }
}

// ---------- weight precompute: all 6 W matrices -> bf16 [n][k] image ----
// Plain col-major-by-output layout: wbuf[off + n*128 + k]. B-fragments are
// contiguous 16B runs read straight from global (L1-resident) — no LDS.
__global__ void wpk_k(const float* __restrict__ Wl0, const float* __restrict__ Wr0,
                      const float* __restrict__ Wl1, const float* __restrict__ Wr1,
                      const float* __restrict__ Wl2, const float* __restrict__ Wr2,
                      ushort* __restrict__ wbuf) {
  int idx = blockIdx.x * 256 + threadIdx.x;  // 0..81919
  const float* W; int F, r, off;
  if (idx < 16384)      { W = Wl0; F = 128; r = idx;         off = 0; }
  else if (idx < 32768) { W = Wr0; F = 128; r = idx - 16384; off = 16384; }
  else if (idx < 49152) { W = Wl1; F = 128; r = idx - 32768; off = 32768; }
  else if (idx < 65536) { W = Wr1; F = 128; r = idx - 49152; off = 49152; }
  else if (idx < 73728) { W = Wl2; F = 64;  r = idx - 65536; off = 65536; }
  else                  { W = Wr2; F = 64;  r = idx - 73728; off = 73728; }
  int k = r / F, n = r % F;
  wbuf[off + n * 128 + k] = f2bf(W[k * F + n]);
}

// ---------- MFMA dual GEMM, LDS-free ----------
// A-fragments (4 per wave, 16 VGPR) cached from global H (row-major, 64B-line
// coalesced); BN+ReLU applied in registers at load. B-fragments streamed from
// the 32KB/phase weight image (L1-hit). No LDS, no barriers.
template <int F, bool HB16>
__global__ __launch_bounds__(256) void gemm_mfma(
    const void* __restrict__ H, const ushort* __restrict__ Wpre,
    const float* __restrict__ ss, ushort* __restrict__ Tlb,
    ushort* __restrict__ Trb) {
  const int tid = threadIdx.x;
  const int lane = tid & 63;
  const int w = tid >> 6;
  const int col = lane & 15;
  const int quad = lane >> 4;
  const int nb = blockIdx.x * 64;
  const int row = nb + w * 16 + col;

  bf16x8 afrag[4];
#pragma unroll
  for (int s = 0; s < 4; ++s) {
    const int c = s * 4 + quad;   // k-chunk: k = c*8 .. c*8+7
    const int gk = c * 8;
    uint4 hv = {0, 0, 0, 0};
    if (HB16) {
      if (row < NN) hv = *(const uint4*)((const ushort*)H + (size_t)row * 128 + gk);
      uint* p = (uint*)&hv;
      float sc[8], sh[8];
      *(float4*)(sc + 0) = *(const float4*)(ss + gk + 0);
      *(float4*)(sc + 4) = *(const float4*)(ss + gk + 4);
      *(float4*)(sh + 0) = *(const float4*)(ss + 128 + gk + 0);
      *(float4*)(sh + 4) = *(const float4*)(ss + 128 + gk + 4);
#pragma unroll
      for (int j = 0; j < 4; ++j) {
        float f0 = fmaxf(fmaf(bflo(p[j]), sc[2 * j], sh[2 * j]), 0.f);
        float f1 = fmaxf(fmaf(bfhi(p[j]), sc[2 * j + 1], sh[2 * j + 1]), 0.f);
        p[j] = f22bf(f0, f1);
      }
    } else {
      float4 fa = {0.f, 0.f, 0.f, 0.f}, fb = {0.f, 0.f, 0.f, 0.f};
      if (row < NN) {
        fa = *(const float4*)((const float*)H + (size_t)row * 128 + gk);
        fb = *(const float4*)((const float*)H + (size_t)row * 128 + gk + 4);
      }
      uint* p = (uint*)&hv;
      p[0] = f22bf(fa.x, fa.y);
      p[1] = f22bf(fa.z, fa.w);
      p[2] = f22bf(fb.x, fb.y);
      p[3] = f22bf(fb.z, fb.w);
    }
    afrag[s] = *(const bf16x8*)&hv;
  }

  const int nodeb = nb + w * 16 + quad * 4;
  for (int phase = 0; phase < 2; ++phase) {
    const ushort* Wp = Wpre + (size_t)phase * F * 128;
    ushort* Outp = phase ? Trb : Tlb;
#pragma unroll 4
    for (int ct = 0; ct < F / 16; ++ct) {
      const int n = ct * 16 + col;
      f32x4 acc = {0.f, 0.f, 0.f, 0.f};
#pragma unroll
      for (int s = 0; s < 4; ++s) {
        const int c = s * 4 + quad;
        bf16x8 b = *(const bf16x8*)(Wp + (size_t)n * 128 + c * 8);
        acc = __builtin_amdgcn_mfma_f32_16x16x32_bf16(afrag[s], b, acc, 0, 0, 0);
      }
#pragma unroll
      for (int r = 0; r < 4; ++r) {
        const int node = nodeb + r;
        if (node < NN) Outp[(size_t)node * F + ct * 16 + col] = f2bf(acc[r]);
      }
    }
  }
}

// ---------- pull-gather aggregation fused with combine (+BN stats) ----------
template <int F, bool STATS, bool OUTF32>
__global__ __launch_bounds__(256, 8) void gather_combine(
    const ushort* __restrict__ Tlb, const int2* __restrict__ eL,
    const int* __restrict__ rowp, const int* __restrict__ cnt_d,
    const ushort* __restrict__ Trb, const float* __restrict__ invd,
    const float* __restrict__ bias, void* __restrict__ outp,
    float* __restrict__ statsb) {
  constexpr int L = F / 2;        // uint columns per row
  constexpr int NPI = 256 / L;    // nodes in flight per block
  constexpr int NPB = 40;         // 50000/40 = 1250 blocks exact
  const int tid = threadIdx.x;
  const int cp = tid % L;
  const int c = 2 * cp;
  const int nl = tid / L;
  const int n0 = blockIdx.x * NPB;
  const float bx = bias[c], by = bias[c + 1];
  float2 S = {0.f, 0.f}, Q = {0.f, 0.f};
#pragma unroll
  for (int it = 0; it < NPB / NPI; ++it) {
    int n = n0 + it * NPI + nl;
    if constexpr (L == 64) n = __builtin_amdgcn_readfirstlane(n);  // wave-uniform
    int beg = rowp[n];
    int end = beg + cnt_d[n];
    float a0 = 0.f, a1 = 0.f;
    int i = beg;
    for (; i + 2 <= end; i += 2) {
      int2 e0 = eL[i];
      int2 e1 = eL[i + 1];
      uint t0 = ((const uint*)Tlb)[(size_t)e0.x * L + cp];
      uint t1 = ((const uint*)Tlb)[(size_t)e1.x * L + cp];
      float w0 = __int_as_float(e0.y);
      float w1 = __int_as_float(e1.y);
      a0 = fmaf(w0, bflo(t0), a0);
      a1 = fmaf(w0, bfhi(t0), a1);
      a0 = fmaf(w1, bflo(t1), a0);
      a1 = fmaf(w1, bfhi(t1), a1);
    }
    if (i < end) {
      int2 e0 = eL[i];
      uint t0 = ((const uint*)Tlb)[(size_t)e0.x * L + cp];
      float w0 = __int_as_float(e0.y);
      a0 = fmaf(w0, bflo(t0), a0);
      a1 = fmaf(w0, bfhi(t0), a1);
    }
    float iv = invd[n];
    uint tb = ((const uint*)Trb)[(size_t)n * L + cp];
    float2 v;
    v.x = fmaf(a0, iv, bflo(tb) + bx);
    v.y = fmaf(a1, iv, bfhi(tb) + by);
    if (OUTF32) *(float2*)((float*)outp + (size_t)n * F + c) = v;
    else ((uint*)outp)[(size_t)n * L + cp] = f22bf(v.x, v.y);
    if constexpr (STATS) {
      S.x += v.x; S.y += v.y;
      Q.x += v.x * v.x; Q.y += v.y * v.y;
    }
  }
  if constexpr (STATS) {
    __shared__ float2 sS[4][L];
    __shared__ float2 sQ[4][L];
    const int wid = tid >> 6, wl = tid & 63;
    if constexpr (L == 64) {
      sS[wid][wl] = S;
      sQ[wid][wl] = Q;
    } else {
      S.x += __shfl_xor(S.x, 32, 64); S.y += __shfl_xor(S.y, 32, 64);
      Q.x += __shfl_xor(Q.x, 32, 64); Q.y += __shfl_xor(Q.y, 32, 64);
      if (wl < 32) { sS[wid][wl] = S; sQ[wid][wl] = Q; }
    }
    __syncthreads();
    if (tid < L) {
      float2 Sa = sS[0][tid], Qa = sQ[0][tid];
#pragma unroll
      for (int w2 = 1; w2 < 4; ++w2) {
        Sa.x += sS[w2][tid].x; Sa.y += sS[w2][tid].y;
        Qa.x += sQ[w2][tid].x; Qa.y += sQ[w2][tid].y;
      }
      float* sb = statsb + (size_t)(blockIdx.x & (SREP - 1)) * 256;
      int col = 2 * tid;
      atomicAdd(&sb[col], Sa.x);
      atomicAdd(&sb[col + 1], Sa.y);
      atomicAdd(&sb[128 + col], Qa.x);
      atomicAdd(&sb[128 + col + 1], Qa.y);
    }
  }
}

// ---------- BN finalize: reduce SREP replicas, then zero them ----------
__global__ void bn_fin(float* __restrict__ statsb, const float* __restrict__ gamma,
                       const float* __restrict__ beta, float* __restrict__ ss) {
  int f = threadIdx.x;
  float sum = 0.f, sq = 0.f;
#pragma unroll 8
  for (int r = 0; r < SREP; ++r) {
    sum += statsb[r * 256 + f];
    sq  += statsb[r * 256 + 128 + f];
    statsb[r * 256 + f] = 0.f;
    statsb[r * 256 + 128 + f] = 0.f;
  }
  float mu = sum * (1.0f / (float)NN);
  float ex2 = sq * (1.0f / (float)NN);
  float var = ex2 - mu * mu;
  float sc = gamma[f] * rsqrtf(var + 1e-5f);
  ss[f] = sc;
  ss[128 + f] = beta[f] - mu * sc;
}

extern "C" void kernel_launch(void* const* d_in, const int* in_sizes, int n_in,
                              void* d_out, int out_size, void* d_ws, size_t ws_size,
                              hipStream_t stream) {
  (void)in_sizes; (void)n_in; (void)out_size; (void)ws_size;
  const float* x   = (const float*)d_in[0];
  const int*   ei  = (const int*)d_in[1];
  const float* ew  = (const float*)d_in[2];
  const float* Wl0 = (const float*)d_in[3];
  const float* Wr0 = (const float*)d_in[4];
  const float* b0  = (const float*)d_in[5];
  const float* Wl1 = (const float*)d_in[6];
  const float* Wr1 = (const float*)d_in[7];
  const float* b1  = (const float*)d_in[8];
  const float* Wl2 = (const float*)d_in[9];
  const float* Wr2 = (const float*)d_in[10];
  const float* b2  = (const float*)d_in[11];
  const float* g0  = (const float*)d_in[12];
  const float* be0 = (const float*)d_in[13];
  const float* g1  = (const float*)d_in[14];
  const float* be1 = (const float*)d_in[15];
  float* out = (float*)d_out;

  size_t off = 0;
  auto alloc = [&](size_t b) -> void* {
    void* p = (char*)d_ws + off;
    off += (b + 255) & ~(size_t)255;
    return p;
  };
  ushort* tlb  = (ushort*)alloc((size_t)NN * 128 * 2);  // 12.8 MB
  ushort* trb  = (ushort*)alloc((size_t)NN * 128 * 2);  // 12.8 MB
  ushort* hpre = (ushort*)alloc((size_t)NN * 128 * 2);  // 12.8 MB (bf16)
  int2* eL     = (int2*)alloc((size_t)EE * 8);          // 4.8 MB (src,w) by dst
  ushort* wbuf = (ushort*)alloc(81920 * 2);             // 160 KB
  int*  cnt_d  = (int*)alloc((size_t)NN * 4);
  int*  cur_d  = (int*)alloc((size_t)NN * 4);
  int*  rowp   = (int*)alloc((size_t)NN * 4);
  int*  bsum   = (int*)alloc(SCB * 4);
  float* invd  = (float*)alloc((size_t)NN * 4);
  float* statsb = (float*)alloc((size_t)SREP * 256 * 4);
  float* ssb   = (float*)alloc(256 * 4);

  const int EB = (EE + 255) / 256;
  const int GEMMB = (NN + 63) / 64;  // 782

  // ---- prep: CSR-by-dst
  hipMemsetAsync(cnt_d, 0, (size_t)NN * 4, stream);
  hipMemsetAsync(statsb, 0, (size_t)SREP * 256 * 4, stream);
  count_k<<<EB, 256, 0, stream>>>(ei, cnt_d);
  wpk_k<<<320, 256, 0, stream>>>(Wl0, Wr0, Wl1, Wr1, Wl2, Wr2, wbuf);
  scanA_k<<<SCB, 256, 0, stream>>>(cnt_d, cur_d, bsum);
  scanB_k<<<1, 64, 0, stream>>>(bsum);
  scanC_k<<<SCB, 256, 0, stream>>>(cur_d, bsum, cnt_d, rowp, invd);
  fill_k<<<EB, 256, 0, stream>>>(ei, ew, cur_d, eL);

  const int GB = NN / 40;  // 1250

  // ---- layer 0 (H = x f32, no BN)
  gemm_mfma<128, false><<<GEMMB, 256, 0, stream>>>(x, wbuf, nullptr, tlb, trb);
  gather_combine<128, true, false><<<GB, 256, 0, stream>>>(tlb, eL, rowp, cnt_d, trb, invd, b0, hpre, statsb);
  bn_fin<<<1, 128, 0, stream>>>(statsb, g0, be0, ssb);

  // ---- layer 1 (H = hpre bf16, BN0+ReLU in registers)
  gemm_mfma<128, true><<<GEMMB, 256, 0, stream>>>(hpre, wbuf + 32768, ssb, tlb, trb);
  gather_combine<128, true, false><<<GB, 256, 0, stream>>>(tlb, eL, rowp, cnt_d, trb, invd, b1, hpre, statsb);
  bn_fin<<<1, 128, 0, stream>>>(statsb, g1, be1, ssb);

  // ---- layer 2 (H = hpre bf16, BN1+ReLU in registers; out f32 to d_out)
  gemm_mfma<64, true><<<GEMMB, 256, 0, stream>>>(hpre, wbuf + 65536, ssb, tlb, trb);
  gather_combine<64, false, true><<<GB, 256, 0, stream>>>(tlb, eL, rowp, cnt_d, trb, invd, b2, out, nullptr);
}

// Round 4
// 312.365 us; speedup vs baseline: 1.2482x; 1.2482x over previous
//
#include <hip/hip_runtime.h>
#include <hip/hip_bf16.h>

#define NN 50000
#define EE 600000
#define SREP 64   // stats replicas (atomic decontention)
#define SCB 49    // scan blocks: 49 x 1024 elems >= NN

typedef short bf16x8 __attribute__((ext_vector_type(8)));
typedef float f32x4 __attribute__((ext_vector_type(4)));

__device__ inline ushort f2bf(float x) {  // round-to-nearest-even bf16
  unsigned u = __float_as_uint(x);
  u = (u + 0x7fffu + ((u >> 16) & 1u)) >> 16;
  return (ushort)u;
}
__device__ inline float bflo(uint t) { return __uint_as_float(t << 16); }
__device__ inline float bfhi(uint t) { return __uint_as_float(t & 0xffff0000u); }
__device__ inline uint f22bf(float a, float b) { return ((uint)f2bf(b) << 16) | (uint)f2bf(a); }

// ---------- graph preprocessing (CSR by destination) ----------
__global__ void count_k(const int* __restrict__ ei, int* __restrict__ cnt_d) {
  int e = blockIdx.x * 256 + threadIdx.x;
  if (e < EE) atomicAdd(&cnt_d[ei[EE + e]], 1);
}

__global__ __launch_bounds__(256) void scanA_k(const int* __restrict__ cnt,
                                               int* __restrict__ cur,
                                               int* __restrict__ bsum) {
  __shared__ int ls[256];
  const int t = threadIdx.x;
  const int base = blockIdx.x * 1024 + t * 4;
  int4 v = {0, 0, 0, 0};
  if (base + 3 < NN) v = *(const int4*)(cnt + base);
  else {
    if (base + 0 < NN) v.x = cnt[base + 0];
    if (base + 1 < NN) v.y = cnt[base + 1];
    if (base + 2 < NN) v.z = cnt[base + 2];
  }
  ls[t] = v.x + v.y + v.z + v.w;
  __syncthreads();
  for (int off = 1; off < 256; off <<= 1) {
    int u = (t >= off) ? ls[t - off] : 0;
    __syncthreads();
    ls[t] += u;
    __syncthreads();
  }
  int ex = (t == 0) ? 0 : ls[t - 1];
  int4 o;
  o.x = ex;
  o.y = ex + v.x;
  o.z = o.y + v.y;
  o.w = o.z + v.z;
  if (base + 3 < NN) *(int4*)(cur + base) = o;
  else {
    if (base + 0 < NN) cur[base + 0] = o.x;
    if (base + 1 < NN) cur[base + 1] = o.y;
    if (base + 2 < NN) cur[base + 2] = o.z;
  }
  if (t == 255) bsum[blockIdx.x] = ls[255];
}

__global__ __launch_bounds__(64) void scanB_k(int* __restrict__ bsum) {
  int t = threadIdx.x;
  int own = (t < SCB) ? bsum[t] : 0;
  int v = own;
#pragma unroll
  for (int off = 1; off < 64; off <<= 1) {
    int u = __shfl_up(v, off, 64);
    if (t >= off) v += u;
  }
  if (t < SCB) bsum[t] = v - own;
}

// writes final exclusive scan to BOTH rowp (kept) and cur (bumped by fill_k)
__global__ __launch_bounds__(256) void scanC_k(int* __restrict__ cur,
                                               const int* __restrict__ bsum,
                                               const int* __restrict__ cnt_d,
                                               int* __restrict__ rowp,
                                               float* __restrict__ invd) {
  const int t = threadIdx.x;
  const int base = blockIdx.x * 1024 + t * 4;
  const int off = bsum[blockIdx.x];
  if (base + 3 < NN) {
    int4 v = *(int4*)(cur + base);
    v.x += off; v.y += off; v.z += off; v.w += off;
    *(int4*)(cur + base) = v;
    *(int4*)(rowp + base) = v;
    int4 cd = *(const int4*)(cnt_d + base);
    float4 iv;
    iv.x = 1.0f / (float)max(cd.x, 1);
    iv.y = 1.0f / (float)max(cd.y, 1);
    iv.z = 1.0f / (float)max(cd.z, 1);
    iv.w = 1.0f / (float)max(cd.w, 1);
    *(float4*)(invd + base) = iv;
  } else {
    for (int i = 0; i < 4; ++i) {
      if (base + i < NN) {
        int v = cur[base + i] + off;
        cur[base + i] = v;
        rowp[base + i] = v;
        invd[base + i] = 1.0f / (float)max(cnt_d[base + i], 1);
      }
    }
  }
}

__global__ void fill_k(const int* __restrict__ ei, const float* __restrict__ ew,
                       int* __restrict__ cur_d, int2* __restrict__ eL) {
  int e = blockIdx.x * 256 + threadIdx.x;
  if (e < EE) {
    int s = ei[e], d = ei[EE + e];
    int pc = atomicAdd(&cur_d[d], 1);
    int2 v;
    v.x = s;
    v.y = __float_as_int(ew[e]);
    eL[pc] = v;
  }
}

// ---------- weight precompute: all 6 W matrices -> bf16 swizzled image ----
// (round-1 layout: XOR-swizzled for conflict-free ds_read_b128)
__global__ void wpk_k(const float* __restrict__ Wl0, const float* __restrict__ Wr0,
                      const float* __restrict__ Wl1, const float* __restrict__ Wr1,
                      const float* __restrict__ Wl2, const float* __restrict__ Wr2,
                      ushort* __restrict__ wbuf) {
  int idx = blockIdx.x * 256 + threadIdx.x;  // 0..81919
  const float* W; int F, r, off;
  if (idx < 16384)      { W = Wl0; F = 128; r = idx;         off = 0; }
  else if (idx < 32768) { W = Wr0; F = 128; r = idx - 16384; off = 16384; }
  else if (idx < 49152) { W = Wl1; F = 128; r = idx - 32768; off = 32768; }
  else if (idx < 65536) { W = Wr1; F = 128; r = idx - 49152; off = 49152; }
  else if (idx < 73728) { W = Wl2; F = 64;  r = idx - 65536; off = 65536; }
  else                  { W = Wr2; F = 64;  r = idx - 73728; off = 73728; }
  int k = r / F, n = r % F;
  wbuf[off + n * 128 + ((((k >> 3) + n) & 15) << 3) + (k & 7)] = f2bf(W[k * F + n]);
}

// ---------- MFMA dual GEMM, hybrid: A from global regs, B from LDS ----------
// 128 rows/block, 2 row-tiles per wave sharing each B ds_read (4 ds_read ->
// 8 MFMA per ct). No Hs staging. BN+ReLU applied in registers at A-load.
template <int F, bool HB16>
__global__ __launch_bounds__(256) void gemm_mfma(
    const void* __restrict__ H, const ushort* __restrict__ Wpre,
    const float* __restrict__ ss, ushort* __restrict__ Tlb,
    ushort* __restrict__ Trb) {
  __shared__ __align__(16) ushort Wt[F * 128];
  const int tid = threadIdx.x;
  const int lane = tid & 63;
  const int w = tid >> 6;
  const int col = lane & 15;
  const int quad = lane >> 4;
  const int nb = blockIdx.x * 128;

  bf16x8 afrag[2][4];
#pragma unroll
  for (int t2 = 0; t2 < 2; ++t2) {
    const int row = nb + w * 32 + t2 * 16 + col;
#pragma unroll
    for (int s = 0; s < 4; ++s) {
      const int c = s * 4 + quad;   // k-chunk: k = c*8 .. c*8+7
      const int gk = c * 8;
      uint4 hv = {0, 0, 0, 0};
      if (HB16) {
        if (row < NN) hv = *(const uint4*)((const ushort*)H + (size_t)row * 128 + gk);
        uint* p = (uint*)&hv;
#pragma unroll
        for (int j = 0; j < 4; ++j) {
          float f0 = fmaxf(fmaf(bflo(p[j]), ss[gk + 2 * j], ss[128 + gk + 2 * j]), 0.f);
          float f1 = fmaxf(fmaf(bfhi(p[j]), ss[gk + 2 * j + 1], ss[128 + gk + 2 * j + 1]), 0.f);
          p[j] = f22bf(f0, f1);
        }
      } else {
        float4 fa = {0.f, 0.f, 0.f, 0.f}, fb = {0.f, 0.f, 0.f, 0.f};
        if (row < NN) {
          fa = *(const float4*)((const float*)H + (size_t)row * 128 + gk);
          fb = *(const float4*)((const float*)H + (size_t)row * 128 + gk + 4);
        }
        uint* p = (uint*)&hv;
        p[0] = f22bf(fa.x, fa.y);
        p[1] = f22bf(fa.z, fa.w);
        p[2] = f22bf(fb.x, fb.y);
        p[3] = f22bf(fb.z, fb.w);
      }
      afrag[t2][s] = *(const bf16x8*)&hv;
    }
  }

  for (int phase = 0; phase < 2; ++phase) {
    const uint4* src = (const uint4*)(Wpre + phase * F * 128);
    __syncthreads();
    for (int i = tid; i < F * 16; i += 256) ((uint4*)Wt)[i] = src[i];
    __syncthreads();
    ushort* Outp = phase ? Trb : Tlb;
#pragma unroll 2
    for (int ct = 0; ct < F / 16; ++ct) {
      const int n = ct * 16 + col;
      f32x4 acc0 = {0.f, 0.f, 0.f, 0.f};
      f32x4 acc1 = {0.f, 0.f, 0.f, 0.f};
#pragma unroll
      for (int s = 0; s < 4; ++s) {
        const int c = s * 4 + quad;
        bf16x8 b = *(const bf16x8*)&Wt[n * 128 + (((c + n) & 15) << 3)];
        acc0 = __builtin_amdgcn_mfma_f32_16x16x32_bf16(afrag[0][s], b, acc0, 0, 0, 0);
        acc1 = __builtin_amdgcn_mfma_f32_16x16x32_bf16(afrag[1][s], b, acc1, 0, 0, 0);
      }
      const int cc = ct * 16 + col;
      const int nodeb0 = nb + w * 32 + quad * 4;
#pragma unroll
      for (int r = 0; r < 4; ++r) {
        const int node = nodeb0 + r;
        if (node < NN) Outp[(size_t)node * F + cc] = f2bf(acc0[r]);
      }
#pragma unroll
      for (int r = 0; r < 4; ++r) {
        const int node = nodeb0 + 16 + r;
        if (node < NN) Outp[(size_t)node * F + cc] = f2bf(acc1[r]);
      }
    }
  }
}

// ---------- pull-gather aggregation fused with combine (+BN stats) ----------
// Per dst node, L lanes cooperate. Edge records preloaded cooperatively
// (one coalesced int2 load per L edges), broadcast via __shfl; Tlb row loads
// 4-deep pipelined (MLP 4). NPB shrunk for 32 waves/CU latency hiding.
template <int F, bool STATS, bool OUTF32>
__global__ __launch_bounds__(256, 8) void gather_combine(
    const ushort* __restrict__ Tlb, const int2* __restrict__ eL,
    const int* __restrict__ rowp, const int* __restrict__ cnt_d,
    const ushort* __restrict__ Trb, const float* __restrict__ invd,
    const float* __restrict__ bias, void* __restrict__ outp,
    float* __restrict__ statsb) {
  constexpr int L = F / 2;              // lanes (uint columns) per node
  constexpr int NPI = 256 / L;          // nodes per block-iteration
  constexpr int NPB = (L == 64) ? 20 : 16;  // 2500 / 3125 blocks (exact)
  const int tid = threadIdx.x;
  const int cp = tid % L;
  const int c = 2 * cp;
  const int nl = tid / L;
  const int n0 = blockIdx.x * NPB;
  const float bx = bias[c], by = bias[c + 1];
  float2 S = {0.f, 0.f}, Q = {0.f, 0.f};
#pragma unroll
  for (int it = 0; it < NPB / NPI; ++it) {
    int n = n0 + it * NPI + nl;
    if constexpr (L == 64) n = __builtin_amdgcn_readfirstlane(n);  // wave-uniform
    const int beg = rowp[n];
    const int deg = cnt_d[n];
    float a0 = 0.f, a1 = 0.f;
    for (int base = 0; base < deg; base += L) {
      const int take = deg - base;
      int2 er = {0, 0};
      if (cp < take) er = eL[beg + base + cp];
      int m = take < L ? take : L;
      if constexpr (L == 32) m = max(m, __shfl_xor(m, 32, 64));  // wave-uniform bound
      int j = 0;
      for (; j + 4 <= m; j += 4) {
        int s0 = __shfl(er.x, j + 0, L);
        int s1 = __shfl(er.x, j + 1, L);
        int s2 = __shfl(er.x, j + 2, L);
        int s3 = __shfl(er.x, j + 3, L);
        float w0 = __int_as_float(__shfl(er.y, j + 0, L));
        float w1 = __int_as_float(__shfl(er.y, j + 1, L));
        float w2 = __int_as_float(__shfl(er.y, j + 2, L));
        float w3 = __int_as_float(__shfl(er.y, j + 3, L));
        uint t0 = ((const uint*)Tlb)[(size_t)s0 * L + cp];
        uint t1 = ((const uint*)Tlb)[(size_t)s1 * L + cp];
        uint t2 = ((const uint*)Tlb)[(size_t)s2 * L + cp];
        uint t3 = ((const uint*)Tlb)[(size_t)s3 * L + cp];
        a0 = fmaf(w0, bflo(t0), a0); a1 = fmaf(w0, bfhi(t0), a1);
        a0 = fmaf(w1, bflo(t1), a0); a1 = fmaf(w1, bfhi(t1), a1);
        a0 = fmaf(w2, bflo(t2), a0); a1 = fmaf(w2, bfhi(t2), a1);
        a0 = fmaf(w3, bflo(t3), a0); a1 = fmaf(w3, bfhi(t3), a1);
      }
      for (; j < m; ++j) {
        int s0 = __shfl(er.x, j, L);
        float w0 = __int_as_float(__shfl(er.y, j, L));
        uint t0 = ((const uint*)Tlb)[(size_t)s0 * L + cp];
        a0 = fmaf(w0, bflo(t0), a0);
        a1 = fmaf(w0, bfhi(t0), a1);
      }
    }
    float iv = invd[n];
    uint tb = ((const uint*)Trb)[(size_t)n * L + cp];
    float2 v;
    v.x = fmaf(a0, iv, bflo(tb) + bx);
    v.y = fmaf(a1, iv, bfhi(tb) + by);
    if (OUTF32) *(float2*)((float*)outp + (size_t)n * F + c) = v;
    else ((uint*)outp)[(size_t)n * L + cp] = f22bf(v.x, v.y);
    if constexpr (STATS) {
      S.x += v.x; S.y += v.y;
      Q.x += v.x * v.x; Q.y += v.y * v.y;
    }
  }
  if constexpr (STATS) {
    __shared__ float2 sS[4][L];
    __shared__ float2 sQ[4][L];
    const int wid = tid >> 6, wl = tid & 63;
    if constexpr (L == 64) {
      sS[wid][wl] = S;
      sQ[wid][wl] = Q;
    } else {
      S.x += __shfl_xor(S.x, 32, 64); S.y += __shfl_xor(S.y, 32, 64);
      Q.x += __shfl_xor(Q.x, 32, 64); Q.y += __shfl_xor(Q.y, 32, 64);
      if (wl < 32) { sS[wid][wl] = S; sQ[wid][wl] = Q; }
    }
    __syncthreads();
    if (tid < L) {
      float2 Sa = sS[0][tid], Qa = sQ[0][tid];
#pragma unroll
      for (int w2 = 1; w2 < 4; ++w2) {
        Sa.x += sS[w2][tid].x; Sa.y += sS[w2][tid].y;
        Qa.x += sQ[w2][tid].x; Qa.y += sQ[w2][tid].y;
      }
      float* sb = statsb + (size_t)(blockIdx.x & (SREP - 1)) * 256;
      int col = 2 * tid;
      atomicAdd(&sb[col], Sa.x);
      atomicAdd(&sb[col + 1], Sa.y);
      atomicAdd(&sb[128 + col], Qa.x);
      atomicAdd(&sb[128 + col + 1], Qa.y);
    }
  }
}

// ---------- BN finalize: reduce SREP replicas, then zero them ----------
__global__ void bn_fin(float* __restrict__ statsb, const float* __restrict__ gamma,
                       const float* __restrict__ beta, float* __restrict__ ss) {
  int f = threadIdx.x;
  float sum = 0.f, sq = 0.f;
#pragma unroll 8
  for (int r = 0; r < SREP; ++r) {
    sum += statsb[r * 256 + f];
    sq  += statsb[r * 256 + 128 + f];
    statsb[r * 256 + f] = 0.f;
    statsb[r * 256 + 128 + f] = 0.f;
  }
  float mu = sum * (1.0f / (float)NN);
  float ex2 = sq * (1.0f / (float)NN);
  float var = ex2 - mu * mu;
  float sc = gamma[f] * rsqrtf(var + 1e-5f);
  ss[f] = sc;
  ss[128 + f] = beta[f] - mu * sc;
}

extern "C" void kernel_launch(void* const* d_in, const int* in_sizes, int n_in,
                              void* d_out, int out_size, void* d_ws, size_t ws_size,
                              hipStream_t stream) {
  (void)in_sizes; (void)n_in; (void)out_size; (void)ws_size;
  const float* x   = (const float*)d_in[0];
  const int*   ei  = (const int*)d_in[1];
  const float* ew  = (const float*)d_in[2];
  const float* Wl0 = (const float*)d_in[3];
  const float* Wr0 = (const float*)d_in[4];
  const float* b0  = (const float*)d_in[5];
  const float* Wl1 = (const float*)d_in[6];
  const float* Wr1 = (const float*)d_in[7];
  const float* b1  = (const float*)d_in[8];
  const float* Wl2 = (const float*)d_in[9];
  const float* Wr2 = (const float*)d_in[10];
  const float* b2  = (const float*)d_in[11];
  const float* g0  = (const float*)d_in[12];
  const float* be0 = (const float*)d_in[13];
  const float* g1  = (const float*)d_in[14];
  const float* be1 = (const float*)d_in[15];
  float* out = (float*)d_out;

  size_t off = 0;
  auto alloc = [&](size_t b) -> void* {
    void* p = (char*)d_ws + off;
    off += (b + 255) & ~(size_t)255;
    return p;
  };
  ushort* tlb  = (ushort*)alloc((size_t)NN * 128 * 2);  // 12.8 MB
  ushort* trb  = (ushort*)alloc((size_t)NN * 128 * 2);  // 12.8 MB
  ushort* hpre = (ushort*)alloc((size_t)NN * 128 * 2);  // 12.8 MB (bf16)
  int2* eL     = (int2*)alloc((size_t)EE * 8);          // 4.8 MB (src,w) by dst
  ushort* wbuf = (ushort*)alloc(81920 * 2);             // 160 KB
  int*  cnt_d  = (int*)alloc((size_t)NN * 4);
  int*  cur_d  = (int*)alloc((size_t)NN * 4);
  int*  rowp   = (int*)alloc((size_t)NN * 4);
  int*  bsum   = (int*)alloc(SCB * 4);
  float* invd  = (float*)alloc((size_t)NN * 4);
  float* statsb = (float*)alloc((size_t)SREP * 256 * 4);
  float* ssb   = (float*)alloc(256 * 4);

  const int EB = (EE + 255) / 256;
  const int GEMMB = (NN + 127) / 128;  // 391

  // ---- prep: CSR-by-dst
  hipMemsetAsync(cnt_d, 0, (size_t)NN * 4, stream);
  hipMemsetAsync(statsb, 0, (size_t)SREP * 256 * 4, stream);
  count_k<<<EB, 256, 0, stream>>>(ei, cnt_d);
  wpk_k<<<320, 256, 0, stream>>>(Wl0, Wr0, Wl1, Wr1, Wl2, Wr2, wbuf);
  scanA_k<<<SCB, 256, 0, stream>>>(cnt_d, cur_d, bsum);
  scanB_k<<<1, 64, 0, stream>>>(bsum);
  scanC_k<<<SCB, 256, 0, stream>>>(cur_d, bsum, cnt_d, rowp, invd);
  fill_k<<<EB, 256, 0, stream>>>(ei, ew, cur_d, eL);

  const int GB128 = NN / 20;  // 2500
  const int GB64  = NN / 16;  // 3125

  // ---- layer 0 (H = x f32, no BN)
  gemm_mfma<128, false><<<GEMMB, 256, 0, stream>>>(x, wbuf, nullptr, tlb, trb);
  gather_combine<128, true, false><<<GB128, 256, 0, stream>>>(tlb, eL, rowp, cnt_d, trb, invd, b0, hpre, statsb);
  bn_fin<<<1, 128, 0, stream>>>(statsb, g0, be0, ssb);

  // ---- layer 1 (H = hpre bf16, BN0+ReLU in registers)
  gemm_mfma<128, true><<<GEMMB, 256, 0, stream>>>(hpre, wbuf + 32768, ssb, tlb, trb);
  gather_combine<128, true, false><<<GB128, 256, 0, stream>>>(tlb, eL, rowp, cnt_d, trb, invd, b1, hpre, statsb);
  bn_fin<<<1, 128, 0, stream>>>(statsb, g1, be1, ssb);

  // ---- layer 2 (H = hpre bf16, BN1+ReLU in registers; out f32 to d_out)
  gemm_mfma<64, true><<<GEMMB, 256, 0, stream>>>(hpre, wbuf + 65536, ssb, tlb, trb);
  gather_combine<64, false, true><<<GB64, 256, 0, stream>>>(tlb, eL, rowp, cnt_d, trb, invd, b2, out, nullptr);
}

// Round 5
// 303.174 us; speedup vs baseline: 1.2860x; 1.0303x over previous
//
#include <hip/hip_runtime.h>
#include <hip/hip_bf16.h>

#define NN 50000
#define EE 600000
#define SREP 64   // stats replicas (atomic decontention)
#define SCB 49    // scan blocks: 49 x 1024 elems >= NN

typedef short bf16x8 __attribute__((ext_vector_type(8)));
typedef float f32x4 __attribute__((ext_vector_type(4)));

__device__ inline ushort f2bf(float x) {  // round-to-nearest-even bf16
  unsigned u = __float_as_uint(x);
  u = (u + 0x7fffu + ((u >> 16) & 1u)) >> 16;
  return (ushort)u;
}
__device__ inline float bflo(uint t) { return __uint_as_float(t << 16); }
__device__ inline float bfhi(uint t) { return __uint_as_float(t & 0xffff0000u); }
__device__ inline uint f22bf(float a, float b) { return ((uint)f2bf(b) << 16) | (uint)f2bf(a); }

#define EB 2344   // (EE+255)/256

// ---------- fused: edge dst-count + weight precompute ----------
// blocks [0,EB): count; blocks [EB, EB+320): pack all 6 W into bf16 swizzled
// image (XOR-swizzled for conflict-free ds_read_b128 in gemm).
__global__ void prep0_k(const int* __restrict__ ei, int* __restrict__ cnt_d,
                        const float* __restrict__ Wl0, const float* __restrict__ Wr0,
                        const float* __restrict__ Wl1, const float* __restrict__ Wr1,
                        const float* __restrict__ Wl2, const float* __restrict__ Wr2,
                        ushort* __restrict__ wbuf) {
  const int b = blockIdx.x;
  if (b < EB) {
    int e = b * 256 + threadIdx.x;
    if (e < EE) atomicAdd(&cnt_d[ei[EE + e]], 1);
  } else {
    int idx = (b - EB) * 256 + threadIdx.x;  // 0..81919
    const float* W; int F, r, off;
    if (idx < 16384)      { W = Wl0; F = 128; r = idx;         off = 0; }
    else if (idx < 32768) { W = Wr0; F = 128; r = idx - 16384; off = 16384; }
    else if (idx < 49152) { W = Wl1; F = 128; r = idx - 32768; off = 32768; }
    else if (idx < 65536) { W = Wr1; F = 128; r = idx - 49152; off = 49152; }
    else if (idx < 73728) { W = Wl2; F = 64;  r = idx - 65536; off = 65536; }
    else                  { W = Wr2; F = 64;  r = idx - 73728; off = 73728; }
    int k = r / F, n = r % F;
    wbuf[off + n * 128 + ((((k >> 3) + n) & 15) << 3) + (k & 7)] = f2bf(W[k * F + n]);
  }
}

__global__ __launch_bounds__(256) void scanA_k(const int* __restrict__ cnt,
                                               int* __restrict__ cur,
                                               int* __restrict__ bsum) {
  __shared__ int ls[256];
  const int t = threadIdx.x;
  const int base = blockIdx.x * 1024 + t * 4;
  int4 v = {0, 0, 0, 0};
  if (base + 3 < NN) v = *(const int4*)(cnt + base);
  else {
    if (base + 0 < NN) v.x = cnt[base + 0];
    if (base + 1 < NN) v.y = cnt[base + 1];
    if (base + 2 < NN) v.z = cnt[base + 2];
  }
  ls[t] = v.x + v.y + v.z + v.w;
  __syncthreads();
  for (int off = 1; off < 256; off <<= 1) {
    int u = (t >= off) ? ls[t - off] : 0;
    __syncthreads();
    ls[t] += u;
    __syncthreads();
  }
  int ex = (t == 0) ? 0 : ls[t - 1];
  int4 o;
  o.x = ex;
  o.y = ex + v.x;
  o.z = o.y + v.y;
  o.w = o.z + v.z;
  if (base + 3 < NN) *(int4*)(cur + base) = o;
  else {
    if (base + 0 < NN) cur[base + 0] = o.x;
    if (base + 1 < NN) cur[base + 1] = o.y;
    if (base + 2 < NN) cur[base + 2] = o.z;
  }
  if (t == 255) bsum[blockIdx.x] = ls[255];
}

// scanB inlined: each block redundantly wave-scans the 49 block sums.
// Writes final exclusive scan to BOTH rowp (kept) and cur (bumped by fill_k).
__global__ __launch_bounds__(256) void scanC_k(int* __restrict__ cur,
                                               const int* __restrict__ bsum,
                                               const int* __restrict__ cnt_d,
                                               int* __restrict__ rowp,
                                               float* __restrict__ invd) {
  __shared__ int soff;
  const int t = threadIdx.x;
  if (t < 64) {
    int own = (t < SCB) ? bsum[t] : 0;
    int v = own;
#pragma unroll
    for (int o = 1; o < 64; o <<= 1) {
      int u = __shfl_up(v, o, 64);
      if (t >= o) v += u;
    }
    int incl = __shfl(v, blockIdx.x, 64);
    int ownb = __shfl(own, blockIdx.x, 64);
    if (t == 0) soff = incl - ownb;  // exclusive prefix at this block
  }
  __syncthreads();
  const int off = soff;
  const int base = blockIdx.x * 1024 + t * 4;
  if (base + 3 < NN) {
    int4 v = *(int4*)(cur + base);
    v.x += off; v.y += off; v.z += off; v.w += off;
    *(int4*)(cur + base) = v;
    *(int4*)(rowp + base) = v;
    int4 cd = *(const int4*)(cnt_d + base);
    float4 iv;
    iv.x = 1.0f / (float)max(cd.x, 1);
    iv.y = 1.0f / (float)max(cd.y, 1);
    iv.z = 1.0f / (float)max(cd.z, 1);
    iv.w = 1.0f / (float)max(cd.w, 1);
    *(float4*)(invd + base) = iv;
  } else {
    for (int i = 0; i < 4; ++i) {
      if (base + i < NN) {
        int v = cur[base + i] + off;
        cur[base + i] = v;
        rowp[base + i] = v;
        invd[base + i] = 1.0f / (float)max(cnt_d[base + i], 1);
      }
    }
  }
}

__global__ void fill_k(const int* __restrict__ ei, const float* __restrict__ ew,
                       int* __restrict__ cur_d, int2* __restrict__ eL) {
  int e = blockIdx.x * 256 + threadIdx.x;
  if (e < EE) {
    int s = ei[e], d = ei[EE + e];
    int pc = atomicAdd(&cur_d[d], 1);
    int2 v;
    v.x = s;
    v.y = __float_as_int(ew[e]);
    eL[pc] = v;
  }
}

// ---------- MFMA dual GEMM, hybrid: A from global regs, B from LDS ----------
// 128 rows/block, 2 row-tiles per wave sharing each B ds_read. When HB16, the
// BN finalize (formerly a single-block kernel) is replicated per-block: reduce
// the SREP stats replicas into LDS ssl[256] = {scale[128], shift[128]}, then
// BN+ReLU applied in registers at A-load. No bn_fin dispatch, no bubble.
template <int F, bool HB16>
__global__ __launch_bounds__(256) void gemm_mfma(
    const void* __restrict__ H, const ushort* __restrict__ Wpre,
    const float* __restrict__ statsb, const float* __restrict__ gamma,
    const float* __restrict__ beta, ushort* __restrict__ Tlb,
    ushort* __restrict__ Trb) {
  __shared__ __align__(16) ushort Wt[F * 128];
  __shared__ float ssl[256];
  const int tid = threadIdx.x;
  const int lane = tid & 63;
  const int w = tid >> 6;
  const int col = lane & 15;
  const int quad = lane >> 4;
  const int nb = blockIdx.x * 128;

  if (HB16) {
    float s = 0.f;
#pragma unroll 8
    for (int r = 0; r < SREP; ++r) s += statsb[r * 256 + tid];
    ssl[tid] = s;
    __syncthreads();
    if (tid < 128) {
      float mu = ssl[tid] * (1.0f / (float)NN);
      float ex2 = ssl[128 + tid] * (1.0f / (float)NN);
      float var = ex2 - mu * mu;
      float sc = gamma[tid] * rsqrtf(var + 1e-5f);
      ssl[tid] = sc;
      ssl[128 + tid] = beta[tid] - mu * sc;
    }
    __syncthreads();
  }

  bf16x8 afrag[2][4];
#pragma unroll
  for (int t2 = 0; t2 < 2; ++t2) {
    const int row = nb + w * 32 + t2 * 16 + col;
#pragma unroll
    for (int s = 0; s < 4; ++s) {
      const int c = s * 4 + quad;   // k-chunk: k = c*8 .. c*8+7
      const int gk = c * 8;
      uint4 hv = {0, 0, 0, 0};
      if (HB16) {
        if (row < NN) hv = *(const uint4*)((const ushort*)H + (size_t)row * 128 + gk);
        uint* p = (uint*)&hv;
#pragma unroll
        for (int j = 0; j < 4; ++j) {
          float f0 = fmaxf(fmaf(bflo(p[j]), ssl[gk + 2 * j], ssl[128 + gk + 2 * j]), 0.f);
          float f1 = fmaxf(fmaf(bfhi(p[j]), ssl[gk + 2 * j + 1], ssl[128 + gk + 2 * j + 1]), 0.f);
          p[j] = f22bf(f0, f1);
        }
      } else {
        float4 fa = {0.f, 0.f, 0.f, 0.f}, fb = {0.f, 0.f, 0.f, 0.f};
        if (row < NN) {
          fa = *(const float4*)((const float*)H + (size_t)row * 128 + gk);
          fb = *(const float4*)((const float*)H + (size_t)row * 128 + gk + 4);
        }
        uint* p = (uint*)&hv;
        p[0] = f22bf(fa.x, fa.y);
        p[1] = f22bf(fa.z, fa.w);
        p[2] = f22bf(fb.x, fb.y);
        p[3] = f22bf(fb.z, fb.w);
      }
      afrag[t2][s] = *(const bf16x8*)&hv;
    }
  }

  for (int phase = 0; phase < 2; ++phase) {
    const uint4* src = (const uint4*)(Wpre + phase * F * 128);
    __syncthreads();
    for (int i = tid; i < F * 16; i += 256) ((uint4*)Wt)[i] = src[i];
    __syncthreads();
    ushort* Outp = phase ? Trb : Tlb;
#pragma unroll 2
    for (int ct = 0; ct < F / 16; ++ct) {
      const int n = ct * 16 + col;
      f32x4 acc0 = {0.f, 0.f, 0.f, 0.f};
      f32x4 acc1 = {0.f, 0.f, 0.f, 0.f};
#pragma unroll
      for (int s = 0; s < 4; ++s) {
        const int c = s * 4 + quad;
        bf16x8 b = *(const bf16x8*)&Wt[n * 128 + (((c + n) & 15) << 3)];
        acc0 = __builtin_amdgcn_mfma_f32_16x16x32_bf16(afrag[0][s], b, acc0, 0, 0, 0);
        acc1 = __builtin_amdgcn_mfma_f32_16x16x32_bf16(afrag[1][s], b, acc1, 0, 0, 0);
      }
      const int cc = ct * 16 + col;
      const int nodeb0 = nb + w * 32 + quad * 4;
#pragma unroll
      for (int r = 0; r < 4; ++r) {
        const int node = nodeb0 + r;
        if (node < NN) Outp[(size_t)node * F + cc] = f2bf(acc0[r]);
      }
#pragma unroll
      for (int r = 0; r < 4; ++r) {
        const int node = nodeb0 + 16 + r;
        if (node < NN) Outp[(size_t)node * F + cc] = f2bf(acc1[r]);
      }
    }
  }
}

// ---------- pull-gather aggregation fused with combine (+BN stats) ----------
// Per dst node, L lanes cooperate. Edge records preloaded cooperatively
// (one coalesced int2 load per L edges), broadcast via __shfl; Tlb row loads
// 4-deep pipelined (MLP 4). NPB sized for 32 waves/CU latency hiding.
template <int F, bool STATS, bool OUTF32>
__global__ __launch_bounds__(256, 8) void gather_combine(
    const ushort* __restrict__ Tlb, const int2* __restrict__ eL,
    const int* __restrict__ rowp, const int* __restrict__ cnt_d,
    const ushort* __restrict__ Trb, const float* __restrict__ invd,
    const float* __restrict__ bias, void* __restrict__ outp,
    float* __restrict__ statsb) {
  constexpr int L = F / 2;              // lanes (uint columns) per node
  constexpr int NPI = 256 / L;          // nodes per block-iteration
  constexpr int NPB = (L == 64) ? 20 : 16;  // 2500 / 3125 blocks (exact)
  const int tid = threadIdx.x;
  const int cp = tid % L;
  const int c = 2 * cp;
  const int nl = tid / L;
  const int n0 = blockIdx.x * NPB;
  const float bx = bias[c], by = bias[c + 1];
  float2 S = {0.f, 0.f}, Q = {0.f, 0.f};
#pragma unroll
  for (int it = 0; it < NPB / NPI; ++it) {
    int n = n0 + it * NPI + nl;
    if constexpr (L == 64) n = __builtin_amdgcn_readfirstlane(n);  // wave-uniform
    const int beg = rowp[n];
    const int deg = cnt_d[n];
    float a0 = 0.f, a1 = 0.f;
    for (int base = 0; base < deg; base += L) {
      const int take = deg - base;
      int2 er = {0, 0};
      if (cp < take) er = eL[beg + base + cp];
      int m = take < L ? take : L;
      if constexpr (L == 32) m = max(m, __shfl_xor(m, 32, 64));  // wave-uniform bound
      int j = 0;
      for (; j + 4 <= m; j += 4) {
        int s0 = __shfl(er.x, j + 0, L);
        int s1 = __shfl(er.x, j + 1, L);
        int s2 = __shfl(er.x, j + 2, L);
        int s3 = __shfl(er.x, j + 3, L);
        float w0 = __int_as_float(__shfl(er.y, j + 0, L));
        float w1 = __int_as_float(__shfl(er.y, j + 1, L));
        float w2 = __int_as_float(__shfl(er.y, j + 2, L));
        float w3 = __int_as_float(__shfl(er.y, j + 3, L));
        uint t0 = ((const uint*)Tlb)[(size_t)s0 * L + cp];
        uint t1 = ((const uint*)Tlb)[(size_t)s1 * L + cp];
        uint t2 = ((const uint*)Tlb)[(size_t)s2 * L + cp];
        uint t3 = ((const uint*)Tlb)[(size_t)s3 * L + cp];
        a0 = fmaf(w0, bflo(t0), a0); a1 = fmaf(w0, bfhi(t0), a1);
        a0 = fmaf(w1, bflo(t1), a0); a1 = fmaf(w1, bfhi(t1), a1);
        a0 = fmaf(w2, bflo(t2), a0); a1 = fmaf(w2, bfhi(t2), a1);
        a0 = fmaf(w3, bflo(t3), a0); a1 = fmaf(w3, bfhi(t3), a1);
      }
      for (; j < m; ++j) {
        int s0 = __shfl(er.x, j, L);
        float w0 = __int_as_float(__shfl(er.y, j, L));
        uint t0 = ((const uint*)Tlb)[(size_t)s0 * L + cp];
        a0 = fmaf(w0, bflo(t0), a0);
        a1 = fmaf(w0, bfhi(t0), a1);
      }
    }
    float iv = invd[n];
    uint tb = ((const uint*)Trb)[(size_t)n * L + cp];
    float2 v;
    v.x = fmaf(a0, iv, bflo(tb) + bx);
    v.y = fmaf(a1, iv, bfhi(tb) + by);
    if (OUTF32) *(float2*)((float*)outp + (size_t)n * F + c) = v;
    else ((uint*)outp)[(size_t)n * L + cp] = f22bf(v.x, v.y);
    if constexpr (STATS) {
      S.x += v.x; S.y += v.y;
      Q.x += v.x * v.x; Q.y += v.y * v.y;
    }
  }
  if constexpr (STATS) {
    __shared__ float2 sS[4][L];
    __shared__ float2 sQ[4][L];
    const int wid = tid >> 6, wl = tid & 63;
    if constexpr (L == 64) {
      sS[wid][wl] = S;
      sQ[wid][wl] = Q;
    } else {
      S.x += __shfl_xor(S.x, 32, 64); S.y += __shfl_xor(S.y, 32, 64);
      Q.x += __shfl_xor(Q.x, 32, 64); Q.y += __shfl_xor(Q.y, 32, 64);
      if (wl < 32) { sS[wid][wl] = S; sQ[wid][wl] = Q; }
    }
    __syncthreads();
    if (tid < L) {
      float2 Sa = sS[0][tid], Qa = sQ[0][tid];
#pragma unroll
      for (int w2 = 1; w2 < 4; ++w2) {
        Sa.x += sS[w2][tid].x; Sa.y += sS[w2][tid].y;
        Qa.x += sQ[w2][tid].x; Qa.y += sQ[w2][tid].y;
      }
      float* sb = statsb + (size_t)(blockIdx.x & (SREP - 1)) * 256;
      int col = 2 * tid;
      atomicAdd(&sb[col], Sa.x);
      atomicAdd(&sb[col + 1], Sa.y);
      atomicAdd(&sb[128 + col], Qa.x);
      atomicAdd(&sb[128 + col + 1], Qa.y);
    }
  }
}

extern "C" void kernel_launch(void* const* d_in, const int* in_sizes, int n_in,
                              void* d_out, int out_size, void* d_ws, size_t ws_size,
                              hipStream_t stream) {
  (void)in_sizes; (void)n_in; (void)out_size; (void)ws_size;
  const float* x   = (const float*)d_in[0];
  const int*   ei  = (const int*)d_in[1];
  const float* ew  = (const float*)d_in[2];
  const float* Wl0 = (const float*)d_in[3];
  const float* Wr0 = (const float*)d_in[4];
  const float* b0  = (const float*)d_in[5];
  const float* Wl1 = (const float*)d_in[6];
  const float* Wr1 = (const float*)d_in[7];
  const float* b1  = (const float*)d_in[8];
  const float* Wl2 = (const float*)d_in[9];
  const float* Wr2 = (const float*)d_in[10];
  const float* b2  = (const float*)d_in[11];
  const float* g0  = (const float*)d_in[12];
  const float* be0 = (const float*)d_in[13];
  const float* g1  = (const float*)d_in[14];
  const float* be1 = (const float*)d_in[15];
  float* out = (float*)d_out;

  size_t off = 0;
  auto alloc = [&](size_t b) -> void* {
    void* p = (char*)d_ws + off;
    off += (b + 255) & ~(size_t)255;
    return p;
  };
  ushort* tlb  = (ushort*)alloc((size_t)NN * 128 * 2);  // 12.8 MB
  ushort* trb  = (ushort*)alloc((size_t)NN * 128 * 2);  // 12.8 MB
  ushort* hpre = (ushort*)alloc((size_t)NN * 128 * 2);  // 12.8 MB (bf16)
  int2* eL     = (int2*)alloc((size_t)EE * 8);          // 4.8 MB (src,w) by dst
  ushort* wbuf = (ushort*)alloc(81920 * 2);             // 160 KB
  // single zero-region: cnt_d + statsb0 + statsb1 (one memset)
  const size_t CNT_B  = ((size_t)NN * 4 + 255) & ~(size_t)255;
  const size_t STAT_B = (size_t)SREP * 256 * 4;         // 64 KB
  char* zb = (char*)alloc(CNT_B + 2 * STAT_B);
  int*   cnt_d   = (int*)zb;
  float* statsb0 = (float*)(zb + CNT_B);
  float* statsb1 = (float*)(zb + CNT_B + STAT_B);
  int*  cur_d  = (int*)alloc((size_t)NN * 4);
  int*  rowp   = (int*)alloc((size_t)NN * 4);
  int*  bsum   = (int*)alloc(SCB * 4);
  float* invd  = (float*)alloc((size_t)NN * 4);

  const int GEMMB = (NN + 127) / 128;  // 391
  const int GB128 = NN / 20;  // 2500
  const int GB64  = NN / 16;  // 3125

  // ---- prep: CSR-by-dst (fused count+wpk; scanB inlined into scanC)
  hipMemsetAsync(zb, 0, CNT_B + 2 * STAT_B, stream);
  prep0_k<<<EB + 320, 256, 0, stream>>>(ei, cnt_d, Wl0, Wr0, Wl1, Wr1, Wl2, Wr2, wbuf);
  scanA_k<<<SCB, 256, 0, stream>>>(cnt_d, cur_d, bsum);
  scanC_k<<<SCB, 256, 0, stream>>>(cur_d, bsum, cnt_d, rowp, invd);
  fill_k<<<EB, 256, 0, stream>>>(ei, ew, cur_d, eL);

  // ---- layer 0 (H = x f32, no BN)
  gemm_mfma<128, false><<<GEMMB, 256, 0, stream>>>(x, wbuf, nullptr, nullptr, nullptr, tlb, trb);
  gather_combine<128, true, false><<<GB128, 256, 0, stream>>>(tlb, eL, rowp, cnt_d, trb, invd, b0, hpre, statsb0);

  // ---- layer 1 (H = hpre bf16, BN0 finalized per-block from statsb0)
  gemm_mfma<128, true><<<GEMMB, 256, 0, stream>>>(hpre, wbuf + 32768, statsb0, g0, be0, tlb, trb);
  gather_combine<128, true, false><<<GB128, 256, 0, stream>>>(tlb, eL, rowp, cnt_d, trb, invd, b1, hpre, statsb1);

  // ---- layer 2 (H = hpre bf16, BN1 finalized per-block from statsb1; out f32)
  gemm_mfma<64, true><<<GEMMB, 256, 0, stream>>>(hpre, wbuf + 65536, statsb1, g1, be1, tlb, trb);
  gather_combine<64, false, true><<<GB64, 256, 0, stream>>>(tlb, eL, rowp, cnt_d, trb, invd, b2, out, nullptr);
}